// Round 3
// baseline (5111.468 us; speedup 1.0000x reference)
//
#include <hip/hip_runtime.h>
#include <hip/hip_bf16.h>

// VQ-VAE forward. Index-critical path reproduces "fp32 ops with fp64 internal
// accumulation, rounded once per op" (deterministic np-ref semantics):
//   h32 = fl32(x@W1 fp64) relu ; z32 = fl32(h32@W2 fp64)
//   nz32 = fl32(sum_fp64 fl32(z32^2)) ; cn32 = fl32(sum_fp64 fl32(c^2))
//   s32  = fl32(fp64 z32.c) ; d = fl32(fl32(nz32 - 2*s32) + cn32) ; argmin fp32
// Decoder fp32 (tolerance-validated). Outputs: recon[16M], loss[1], idx[16384].

#define B_    16384
#define INDIM 1024
#define HID   2048
#define KCB   8192
#define DDIM  128

// ---------------------------------------------------------------------------
// fp32 tiled GEMM (decoder): C = act(A@B + bias). ACT: 1=relu 2=sigmoid
// ---------------------------------------------------------------------------
template <int BM, int BN, int BK, int TM, int TN, int ACT>
__launch_bounds__(256)
__global__ void gemm_f32(const float* __restrict__ A, const float* __restrict__ Bm,
                         const float* __restrict__ bias, float* __restrict__ C,
                         int M, int N, int K)
{
    constexpr int THREADS = (BM / TM) * (BN / TN);
    static_assert(THREADS == 256, "block must be 256");
    __shared__ float As[BK][BM + 4];
    __shared__ float Bs[BK][BN];

    const int t    = threadIdx.x;
    const int m0   = blockIdx.y * BM;
    const int n0   = blockIdx.x * BN;
    const int tCol = (t % (BN / TN)) * TN;
    const int tRow = (t / (BN / TN)) * TM;

    float acc[TM][TN];
#pragma unroll
    for (int i = 0; i < TM; ++i)
#pragma unroll
        for (int j = 0; j < TN; ++j) acc[i][j] = 0.f;

    for (int k0 = 0; k0 < K; k0 += BK) {
#pragma unroll
        for (int i = 0; i < (BM * BK) / (THREADS * 4); ++i) {
            int lin = (t + i * THREADS) * 4;
            int r = lin / BK, c = lin % BK;
            const float4 v = *(const float4*)(A + (size_t)(m0 + r) * K + k0 + c);
            As[c + 0][r] = v.x; As[c + 1][r] = v.y;
            As[c + 2][r] = v.z; As[c + 3][r] = v.w;
        }
#pragma unroll
        for (int i = 0; i < (BK * BN) / (THREADS * 4); ++i) {
            int lin = (t + i * THREADS) * 4;
            int r = lin / BN, c = lin % BN;
            *(float4*)(&Bs[r][c]) = *(const float4*)(Bm + (size_t)(k0 + r) * N + n0 + c);
        }
        __syncthreads();
#pragma unroll
        for (int kk = 0; kk < BK; ++kk) {
            float ra[TM], rb[TN];
#pragma unroll
            for (int i = 0; i < TM; i += 4) {
                float4 v = *(const float4*)(&As[kk][tRow + i]);
                ra[i] = v.x; ra[i + 1] = v.y; ra[i + 2] = v.z; ra[i + 3] = v.w;
            }
#pragma unroll
            for (int j = 0; j < TN; j += 4) {
                float4 v = *(const float4*)(&Bs[kk][tCol + j]);
                rb[j] = v.x; rb[j + 1] = v.y; rb[j + 2] = v.z; rb[j + 3] = v.w;
            }
#pragma unroll
            for (int i = 0; i < TM; ++i)
#pragma unroll
                for (int j = 0; j < TN; ++j) acc[i][j] += ra[i] * rb[j];
        }
        __syncthreads();
    }

    float bb[TN];
#pragma unroll
    for (int j = 0; j < TN; ++j) bb[j] = bias[n0 + tCol + j];
#pragma unroll
    for (int i = 0; i < TM; ++i) {
        float o[TN];
#pragma unroll
        for (int j = 0; j < TN; ++j) {
            float v = acc[i][j] + bb[j];
            if (ACT == 1) v = fmaxf(v, 0.f);
            else if (ACT == 2) v = 1.f / (1.f + __expf(-v));
            o[j] = v;
        }
        float* crow = C + (size_t)(m0 + tRow + i) * N + n0 + tCol;
#pragma unroll
        for (int j4 = 0; j4 < TN / 4; ++j4)
            ((float4*)crow)[j4] = ((float4*)o)[j4];
    }
}

// ---------------------------------------------------------------------------
// fp32-in, fp64-accumulate GEMM, one fp32 rounding at the end (+ optional relu).
// ---------------------------------------------------------------------------
template <int BM, int BN, int BK, int TM, int TN, int ACT>
__launch_bounds__(256)
__global__ void gemm_f64acc(const float* __restrict__ A, const float* __restrict__ Bm,
                            const float* __restrict__ bias, float* __restrict__ Cout,
                            int M, int N, int K)
{
    constexpr int THREADS = (BM / TM) * (BN / TN);
    static_assert(THREADS == 256, "block must be 256");
    __shared__ double As[BK][BM + 2];
    __shared__ double Bs[BK][BN + 2];

    const int t    = threadIdx.x;
    const int m0   = blockIdx.y * BM;
    const int n0   = blockIdx.x * BN;
    const int tCol = (t % (BN / TN)) * TN;
    const int tRow = (t / (BN / TN)) * TM;

    double acc[TM][TN];
#pragma unroll
    for (int i = 0; i < TM; ++i)
#pragma unroll
        for (int j = 0; j < TN; ++j) acc[i][j] = 0.0;

    for (int k0 = 0; k0 < K; k0 += BK) {
        for (int i4 = t; i4 < (BM * BK) / 4; i4 += THREADS) {
            int lin = i4 * 4;
            int r = lin / BK, c = lin % BK;
            const float4 v = *(const float4*)(A + (size_t)(m0 + r) * K + k0 + c);
            As[c + 0][r] = (double)v.x; As[c + 1][r] = (double)v.y;
            As[c + 2][r] = (double)v.z; As[c + 3][r] = (double)v.w;
        }
        for (int i4 = t; i4 < (BK * BN) / 4; i4 += THREADS) {
            int lin = i4 * 4;
            int r = lin / BN, c = lin % BN;
            const float4 v = *(const float4*)(Bm + (size_t)(k0 + r) * N + n0 + c);
            Bs[r][c + 0] = (double)v.x; Bs[r][c + 1] = (double)v.y;
            Bs[r][c + 2] = (double)v.z; Bs[r][c + 3] = (double)v.w;
        }
        __syncthreads();
#pragma unroll
        for (int kk = 0; kk < BK; ++kk) {
            double ra[TM], rb[TN];
#pragma unroll
            for (int i = 0; i < TM; ++i) ra[i] = As[kk][tRow + i];
#pragma unroll
            for (int j = 0; j < TN; ++j) rb[j] = Bs[kk][tCol + j];
#pragma unroll
            for (int i = 0; i < TM; ++i)
#pragma unroll
                for (int j = 0; j < TN; ++j) acc[i][j] += ra[i] * rb[j];
        }
        __syncthreads();
    }

#pragma unroll
    for (int i = 0; i < TM; ++i) {
#pragma unroll
        for (int j = 0; j < TN; ++j) {
            double v = acc[i][j] + (double)bias[n0 + tCol + j];
            float f = (float)v;                 // single fp32 rounding
            if (ACT == 1) f = fmaxf(f, 0.f);
            Cout[(size_t)(m0 + tRow + i) * N + n0 + tCol + j] = f;
        }
    }
}

// ---------------------------------------------------------------------------
// rownorm32[k] = fl32( sum_fp64( fl32(row[k][d]^2) ) ).  One wave per row.
// Used for both codebook (8192x128) and z (16384x128).
// ---------------------------------------------------------------------------
__global__ void rownorm_kernel(const float* __restrict__ M, float* __restrict__ nrm)
{
    int k = blockIdx.x * 4 + (threadIdx.x >> 6);
    int lane = threadIdx.x & 63;
    float2 c = *(const float2*)(M + (size_t)k * DDIM + lane * 2);
    float q0 = c.x * c.x;              // per-element fp32 rounding (np z*z)
    float q1 = c.y * c.y;
    double s = (double)q0 + (double)q1;
#pragma unroll
    for (int off = 32; off > 0; off >>= 1) s += __shfl_down(s, off);
    if (lane == 0) nrm[k] = (float)s;  // single rounding of the fp64 sum
}

// ---------------------------------------------------------------------------
// Phase A: per (64-row, 64-code) tile, s = fp64 dot(z32, c), then fp32 dist
// d = fl32(fl32(nz32 - 2*s32) + cn32); partial argmin -> pv/pi[row][128].
// ---------------------------------------------------------------------------
__launch_bounds__(256)
__global__ void score_argmin(const float* __restrict__ z, const float* __restrict__ cb,
                             const float* __restrict__ nz32, const float* __restrict__ cn32,
                             float* __restrict__ pv, int* __restrict__ pi)
{
    constexpr int BM = 64, BN = 64, BK = 32;
    __shared__ double zs[BM][BK + 1];
    __shared__ double cs[BN][BK + 1];
    __shared__ float  nz_s[BM];
    __shared__ float  cn_s[BN];
    __shared__ float  rv[BM][16];
    __shared__ int    ri[BM][16];

    const int t    = threadIdx.x;
    const int m0   = blockIdx.y * BM;   // rows
    const int n0   = blockIdx.x * BN;   // codes
    const int tCol = (t & 15) * 4;
    const int tRow = (t >> 4) * 4;

    if (t < BM) nz_s[t] = nz32[m0 + t];
    else if (t < BM + BN) cn_s[t - BM] = cn32[n0 + (t - BM)];

    double acc[4][4];
#pragma unroll
    for (int i = 0; i < 4; ++i)
#pragma unroll
        for (int j = 0; j < 4; ++j) acc[i][j] = 0.0;

    for (int k0 = 0; k0 < DDIM; k0 += BK) {
        // z tile: 64 rows x 32 floats = 512 float4 chunks / 256 threads
#pragma unroll
        for (int i = 0; i < 2; ++i) {
            int chunk = t + i * 256;
            int r = chunk >> 3, q = chunk & 7;
            float4 v = *(const float4*)(z + (size_t)(m0 + r) * DDIM + k0 + q * 4);
            zs[r][q * 4 + 0] = (double)v.x; zs[r][q * 4 + 1] = (double)v.y;
            zs[r][q * 4 + 2] = (double)v.z; zs[r][q * 4 + 3] = (double)v.w;
        }
        // cb tile: 64 codes x 32 floats
#pragma unroll
        for (int i = 0; i < 2; ++i) {
            int chunk = t + i * 256;
            int c = chunk >> 3, q = chunk & 7;
            float4 v = *(const float4*)(cb + (size_t)(n0 + c) * DDIM + k0 + q * 4);
            cs[c][q * 4 + 0] = (double)v.x; cs[c][q * 4 + 1] = (double)v.y;
            cs[c][q * 4 + 2] = (double)v.z; cs[c][q * 4 + 3] = (double)v.w;
        }
        __syncthreads();
#pragma unroll
        for (int kk = 0; kk < BK; ++kk) {
            double ra[4], rb[4];
#pragma unroll
            for (int i = 0; i < 4; ++i) ra[i] = zs[tRow + i][kk];
#pragma unroll
            for (int j = 0; j < 4; ++j) rb[j] = cs[tCol + j][kk];
#pragma unroll
            for (int i = 0; i < 4; ++i)
#pragma unroll
                for (int j = 0; j < 4; ++j) acc[i][j] += ra[i] * rb[j];
        }
        __syncthreads();
    }

    // fp32 dist chain exactly as np: fl32(fl32(nz - 2*s32) + cn)
    float bv[4]; int bi[4];
#pragma unroll
    for (int i = 0; i < 4; ++i) { bv[i] = 3.4e38f; bi[i] = 0x7fffffff; }
#pragma unroll
    for (int j = 0; j < 4; ++j) {
        int   code = n0 + tCol + j;
        float cn   = cn_s[tCol + j];
#pragma unroll
        for (int i = 0; i < 4; ++i) {
            float s32 = (float)acc[i][j];              // matmul rounded once
            float d   = (nz_s[tRow + i] - 2.0f * s32) + cn;
            if (d < bv[i]) { bv[i] = d; bi[i] = code; }
        }
    }
#pragma unroll
    for (int i = 0; i < 4; ++i) { rv[tRow + i][t & 15] = bv[i]; ri[tRow + i][t & 15] = bi[i]; }
    __syncthreads();
    if (t < BM) {
        float v = rv[t][0]; int ix = ri[t][0];
#pragma unroll
        for (int g = 1; g < 16; ++g) {
            float ov = rv[t][g]; int oi = ri[t][g];
            if (ov < v || (ov == v && oi < ix)) { v = ov; ix = oi; }
        }
        pv[(size_t)(m0 + t) * 128 + blockIdx.x] = v;
        pi[(size_t)(m0 + t) * 128 + blockIdx.x] = ix;
    }
}

// Phase B: reduce 128 partials per row. One wave per row.
__global__ void argmin_reduce(const float* __restrict__ pv, const int* __restrict__ pi,
                              int* __restrict__ idxout)
{
    int r = blockIdx.x * 4 + (threadIdx.x >> 6);
    int lane = threadIdx.x & 63;
    const float* p = pv + (size_t)r * 128;
    const int*   q = pi + (size_t)r * 128;
    float v  = p[lane];      int ix = q[lane];
    float v2 = p[lane + 64]; int i2 = q[lane + 64];
    if (v2 < v || (v2 == v && i2 < ix)) { v = v2; ix = i2; }
#pragma unroll
    for (int off = 32; off > 0; off >>= 1) {
        float ov = __shfl_down(v, off);
        int   oi = __shfl_down(ix, off);
        if (ov < v || (ov == v && oi < ix)) { v = ov; ix = oi; }
    }
    if (lane == 0) idxout[r] = ix;
}

// Gather z_q = codebook[idx] (fp32) and accumulate sum((z_q - z32)^2) in fp64.
__global__ void gather_zq_loss(const float* __restrict__ z, const float* __restrict__ cb,
                               const int* __restrict__ idx, float* __restrict__ zq,
                               double* __restrict__ acc)
{
    int r = blockIdx.x * 4 + (threadIdx.x >> 6);
    int lane = threadIdx.x & 63;
    int k = idx[r];
    float2 zv = *(const float2*)(z  + (size_t)r * DDIM + lane * 2);
    float2 cv = *(const float2*)(cb + (size_t)k * DDIM + lane * 2);
    *(float2*)(zq + (size_t)r * DDIM + lane * 2) = cv;
    double dx = (double)cv.x - (double)zv.x, dy = (double)cv.y - (double)zv.y;
    double s = dx * dx + dy * dy;
#pragma unroll
    for (int off = 32; off > 0; off >>= 1) s += __shfl_down(s, off);
    if (lane == 0) atomicAdd(acc, s);
}

__global__ void zero_acc_kernel(double* acc)
{
    if (threadIdx.x == 0 && blockIdx.x == 0) *acc = 0.0;
}

__global__ void finalize_kernel(const int* __restrict__ idx, const double* __restrict__ acc,
                                float* __restrict__ out)
{
    int tid = blockIdx.x * 256 + threadIdx.x;
    if (tid < B_) out[16777217 + tid] = (float)idx[tid];
    if (tid == 0) out[16777216] = (float)((*acc) * 1.25 / (double)(B_ * DDIM));
}

// ---------------------------------------------------------------------------
extern "C" void kernel_launch(void* const* d_in, const int* in_sizes, int n_in,
                              void* d_out, int out_size, void* d_ws, size_t ws_size,
                              hipStream_t stream)
{
    const float* x  = (const float*)d_in[0];
    const float* W1 = (const float*)d_in[1];
    const float* b1 = (const float*)d_in[2];
    const float* W2 = (const float*)d_in[3];
    const float* b2 = (const float*)d_in[4];
    const float* cb = (const float*)d_in[5];
    const float* W3 = (const float*)d_in[6];
    const float* b3 = (const float*)d_in[7];
    const float* W4 = (const float*)d_in[8];
    const float* b4 = (const float*)d_in[9];
    float* out = (float*)d_out;

    char* ws = (char*)d_ws;
    // h (fp32, 128MB) live GEMM1->GEMM2, dead until GEMM3. pv/pi alias into it.
    float*  h    = (float*)(ws);                      // 134,217,728 B
    float*  pv   = (float*)(ws);                      //  8,388,608 B (alias)
    int*    pi   = (int*  )(ws + 8388608ull);         //  8,388,608 B (alias)
    float*  z32  = (float*)(ws + 134217728ull);       //  8,388,608 B
    float*  zq   = (float*)(ws + 142606336ull);       //  8,388,608 B
    float*  nz32 = (float*)(ws + 150994944ull);       //     65,536 B
    float*  cn32 = (float*)(ws + 151060480ull);       //     32,768 B
    int*    idx  = (int*  )(ws + 151093248ull);       //     65,536 B
    double* acc  = (double*)(ws + 151158784ull);      //          8 B

    zero_acc_kernel<<<1, 64, 0, stream>>>(acc);
    rownorm_kernel<<<KCB / 4, 256, 0, stream>>>(cb, cn32);

    // h = relu(fl32(x @ W1 + b1)), fp64-acc    [16384,1024]x[1024,2048]
    gemm_f64acc<64, 64, 16, 4, 4, 1><<<dim3(HID / 64, B_ / 64), 256, 0, stream>>>(
        x, W1, b1, h, B_, HID, INDIM);
    // z32 = fl32(h @ W2 + b2), fp64-acc        [16384,2048]x[2048,128]
    gemm_f64acc<32, 128, 16, 2, 8, 0><<<dim3(1, B_ / 32), 256, 0, stream>>>(
        h, W2, b2, z32, B_, DDIM, HID);
    // nz32 = fl32(sum fl32(z^2))
    rownorm_kernel<<<B_ / 4, 256, 0, stream>>>(z32, nz32);
    // fp32-dist score + argmin (two-phase)
    score_argmin<<<dim3(KCB / 64, B_ / 64), 256, 0, stream>>>(z32, cb, nz32, cn32, pv, pi);
    argmin_reduce<<<B_ / 4, 256, 0, stream>>>(pv, pi, idx);
    // z_q gather + commitment-loss accumulation
    gather_zq_loss<<<B_ / 4, 256, 0, stream>>>(z32, cb, idx, zq, acc);
    // h2 = relu(z_q @ W3 + b3), fp32           [16384,128]x[128,2048]
    gemm_f32<128, 128, 16, 8, 8, 1><<<dim3(HID / 128, B_ / 128), 256, 0, stream>>>(
        zq, W3, b3, h, B_, HID, DDIM);
    // recon = sigmoid(h2 @ W4 + b4), fp32      [16384,2048]x[2048,1024]
    gemm_f32<128, 128, 16, 8, 8, 2><<<dim3(INDIM / 128, B_ / 128), 256, 0, stream>>>(
        h, W4, b4, out, B_, INDIM, HID);

    finalize_kernel<<<B_ / 256, 256, 0, stream>>>(idx, acc, out);
}

// Round 4
// 3380.418 us; speedup vs baseline: 1.5121x; 1.5121x over previous
//
#include <hip/hip_runtime.h>
#include <hip/hip_bf16.h>

// VQ-VAE forward. Index path: fp32-per-op semantics w/ fp64 internal accumulation
// (bit-exact vs np ref, validated R3). Decoder: bf16 MFMA (tolerance-validated).
// Outputs (flat fp32): recon[16384*1024], loss[1], indices-as-float[16384].

#define B_    16384
#define INDIM 1024
#define HID   2048
#define KCB   8192
#define DDIM  128

typedef __bf16 bf16x8 __attribute__((ext_vector_type(8)));
typedef float  floatx4 __attribute__((ext_vector_type(4)));

// ---------------------------------------------------------------------------
// fp32-in, fp64-accumulate GEMM, single fp32 rounding (+ optional relu).
// BM=128 BN=64 BK=16, TM=8 strided rows, TN=4 strided cols, 256 threads.
// Accumulation order (kk ascending, k0 ascending) identical to R3 -> bit-exact.
// ---------------------------------------------------------------------------
template <int ACT>
__launch_bounds__(256)
__global__ void gemm_f64acc(const float* __restrict__ A, const float* __restrict__ Bm,
                            const float* __restrict__ bias, float* __restrict__ Cout,
                            int M, int N, int K)
{
    __shared__ double As[16][129];   // transposed [k][m]; odd stride -> clean banks
    __shared__ double Bs[16][64];    // natural [k][n]

    const int t  = threadIdx.x;
    const int m0 = blockIdx.y * 128;
    const int n0 = blockIdx.x * 64;
    const int rg = t >> 4;   // 0..15: rows rg + 16*i
    const int cl = t & 15;   // 0..15: cols cl + 16*j

    double acc[8][4];
#pragma unroll
    for (int i = 0; i < 8; ++i)
#pragma unroll
        for (int j = 0; j < 4; ++j) acc[i][j] = 0.0;

    for (int k0 = 0; k0 < K; k0 += 16) {
#pragma unroll
        for (int s = 0; s < 2; ++s) {           // A tile 128x16
            int lin = (t + s * 256) * 4;
            int r = lin >> 4, c = lin & 15;
            float4 v = *(const float4*)(A + (size_t)(m0 + r) * K + k0 + c);
            As[c + 0][r] = (double)v.x; As[c + 1][r] = (double)v.y;
            As[c + 2][r] = (double)v.z; As[c + 3][r] = (double)v.w;
        }
        {                                        // B tile 16x64
            int r = t >> 4, c4 = (t & 15) * 4;
            float4 v = *(const float4*)(Bm + (size_t)(k0 + r) * N + n0 + c4);
            Bs[r][c4 + 0] = (double)v.x; Bs[r][c4 + 1] = (double)v.y;
            Bs[r][c4 + 2] = (double)v.z; Bs[r][c4 + 3] = (double)v.w;
        }
        __syncthreads();
#pragma unroll
        for (int kk = 0; kk < 16; ++kk) {
            double ra[8], rb[4];
#pragma unroll
            for (int i = 0; i < 8; ++i) ra[i] = As[kk][rg + 16 * i];
#pragma unroll
            for (int j = 0; j < 4; ++j) rb[j] = Bs[kk][cl + 16 * j];
#pragma unroll
            for (int i = 0; i < 8; ++i)
#pragma unroll
                for (int j = 0; j < 4; ++j) acc[i][j] += ra[i] * rb[j];
        }
        __syncthreads();
    }

#pragma unroll
    for (int i = 0; i < 8; ++i)
#pragma unroll
        for (int j = 0; j < 4; ++j) {
            double v = acc[i][j] + (double)bias[n0 + cl + 16 * j];
            float f = (float)v;                  // single fp32 rounding
            if (ACT == 1) f = fmaxf(f, 0.f);
            Cout[(size_t)(m0 + rg + 16 * i) * N + n0 + cl + 16 * j] = f;
        }
}

// ---------------------------------------------------------------------------
// rownorm32[k] = fl32( sum_fp64( fl32(row[k][d]^2) ) ). One wave per row.
// ---------------------------------------------------------------------------
__global__ void rownorm_kernel(const float* __restrict__ M, float* __restrict__ nrm)
{
    int k = blockIdx.x * 4 + (threadIdx.x >> 6);
    int lane = threadIdx.x & 63;
    float2 c = *(const float2*)(M + (size_t)k * DDIM + lane * 2);
    float q0 = c.x * c.x;
    float q1 = c.y * c.y;
    double s = (double)q0 + (double)q1;
#pragma unroll
    for (int off = 32; off > 0; off >>= 1) s += __shfl_down(s, off);
    if (lane == 0) nrm[k] = (float)s;
}

// ---------------------------------------------------------------------------
// Score phase A: fp64 dot(z32,c) per (64-row,64-code) tile, fp32 dist chain
// d = fl32(fl32(nz - 2*s32) + cn); partial argmin -> pv/pi[row][128].
// Columns strided (cl+16j) to kill 4-way LDS read conflicts; math identical.
// ---------------------------------------------------------------------------
__launch_bounds__(256)
__global__ void score_argmin(const float* __restrict__ z, const float* __restrict__ cb,
                             const float* __restrict__ nz32, const float* __restrict__ cn32,
                             float* __restrict__ pv, int* __restrict__ pi)
{
    constexpr int BM = 64, BN = 64, BK = 32;
    __shared__ double zs[BM][BK + 1];
    __shared__ double cs[BN][BK + 1];
    __shared__ float  nz_s[BM];
    __shared__ float  cn_s[BN];
    __shared__ float  rv[BM][16];
    __shared__ int    ri[BM][16];

    const int t    = threadIdx.x;
    const int m0   = blockIdx.y * BM;
    const int n0   = blockIdx.x * BN;
    const int cl   = t & 15;
    const int tRow = (t >> 4) * 4;

    if (t < BM) nz_s[t] = nz32[m0 + t];
    else if (t < BM + BN) cn_s[t - BM] = cn32[n0 + (t - BM)];

    double acc[4][4];
#pragma unroll
    for (int i = 0; i < 4; ++i)
#pragma unroll
        for (int j = 0; j < 4; ++j) acc[i][j] = 0.0;

    for (int k0 = 0; k0 < DDIM; k0 += BK) {
#pragma unroll
        for (int i = 0; i < 2; ++i) {
            int chunk = t + i * 256;
            int r = chunk >> 3, q = chunk & 7;
            float4 v = *(const float4*)(z + (size_t)(m0 + r) * DDIM + k0 + q * 4);
            zs[r][q * 4 + 0] = (double)v.x; zs[r][q * 4 + 1] = (double)v.y;
            zs[r][q * 4 + 2] = (double)v.z; zs[r][q * 4 + 3] = (double)v.w;
        }
#pragma unroll
        for (int i = 0; i < 2; ++i) {
            int chunk = t + i * 256;
            int c = chunk >> 3, q = chunk & 7;
            float4 v = *(const float4*)(cb + (size_t)(n0 + c) * DDIM + k0 + q * 4);
            cs[c][q * 4 + 0] = (double)v.x; cs[c][q * 4 + 1] = (double)v.y;
            cs[c][q * 4 + 2] = (double)v.z; cs[c][q * 4 + 3] = (double)v.w;
        }
        __syncthreads();
#pragma unroll
        for (int kk = 0; kk < BK; ++kk) {
            double ra[4], rb[4];
#pragma unroll
            for (int i = 0; i < 4; ++i) ra[i] = zs[tRow + i][kk];
#pragma unroll
            for (int j = 0; j < 4; ++j) rb[j] = cs[cl + 16 * j][kk];
#pragma unroll
            for (int i = 0; i < 4; ++i)
#pragma unroll
                for (int j = 0; j < 4; ++j) acc[i][j] += ra[i] * rb[j];
        }
        __syncthreads();
    }

    float bv[4]; int bi[4];
#pragma unroll
    for (int i = 0; i < 4; ++i) { bv[i] = 3.4e38f; bi[i] = 0x7fffffff; }
#pragma unroll
    for (int j = 0; j < 4; ++j) {
        int   code = n0 + cl + 16 * j;
        float cn   = cn_s[cl + 16 * j];
#pragma unroll
        for (int i = 0; i < 4; ++i) {
            float s32 = (float)acc[i][j];
            float d   = (nz_s[tRow + i] - 2.0f * s32) + cn;
            if (d < bv[i] || (d == bv[i] && code < bi[i])) { bv[i] = d; bi[i] = code; }
        }
    }
#pragma unroll
    for (int i = 0; i < 4; ++i) { rv[tRow + i][cl] = bv[i]; ri[tRow + i][cl] = bi[i]; }
    __syncthreads();
    if (t < BM) {
        float v = rv[t][0]; int ix = ri[t][0];
#pragma unroll
        for (int g = 1; g < 16; ++g) {
            float ov = rv[t][g]; int oi = ri[t][g];
            if (ov < v || (ov == v && oi < ix)) { v = ov; ix = oi; }
        }
        pv[(size_t)(m0 + t) * 128 + blockIdx.x] = v;
        pi[(size_t)(m0 + t) * 128 + blockIdx.x] = ix;
    }
}

__global__ void argmin_reduce(const float* __restrict__ pv, const int* __restrict__ pi,
                              int* __restrict__ idxout)
{
    int r = blockIdx.x * 4 + (threadIdx.x >> 6);
    int lane = threadIdx.x & 63;
    const float* p = pv + (size_t)r * 128;
    const int*   q = pi + (size_t)r * 128;
    float v  = p[lane];      int ix = q[lane];
    float v2 = p[lane + 64]; int i2 = q[lane + 64];
    if (v2 < v || (v2 == v && i2 < ix)) { v = v2; ix = i2; }
#pragma unroll
    for (int off = 32; off > 0; off >>= 1) {
        float ov = __shfl_down(v, off);
        int   oi = __shfl_down(ix, off);
        if (ov < v || (ov == v && oi < ix)) { v = ov; ix = oi; }
    }
    if (lane == 0) idxout[r] = ix;
}

__global__ void gather_zq_loss(const float* __restrict__ z, const float* __restrict__ cb,
                               const int* __restrict__ idx, float* __restrict__ zq,
                               double* __restrict__ acc)
{
    int r = blockIdx.x * 4 + (threadIdx.x >> 6);
    int lane = threadIdx.x & 63;
    int k = idx[r];
    float2 zv = *(const float2*)(z  + (size_t)r * DDIM + lane * 2);
    float2 cv = *(const float2*)(cb + (size_t)k * DDIM + lane * 2);
    *(float2*)(zq + (size_t)r * DDIM + lane * 2) = cv;
    double dx = (double)cv.x - (double)zv.x, dy = (double)cv.y - (double)zv.y;
    double s = dx * dx + dy * dy;
#pragma unroll
    for (int off = 32; off > 0; off >>= 1) s += __shfl_down(s, off);
    if (lane == 0) atomicAdd(acc, s);
}

__global__ void zero_acc_kernel(double* acc)
{
    if (threadIdx.x == 0 && blockIdx.x == 0) *acc = 0.0;
}

__global__ void finalize_kernel(const int* __restrict__ idx, const double* __restrict__ acc,
                                float* __restrict__ out)
{
    int tid = blockIdx.x * 256 + threadIdx.x;
    if (tid < B_) out[16777217 + tid] = (float)idx[tid];
    if (tid == 0) out[16777216] = (float)((*acc) * 1.25 / (double)(B_ * DDIM));
}

// ---------------------------------------------------------------------------
// One-time weight transpose+cvt: in fp32 [K][N] -> out bf16 [N][K].
// ---------------------------------------------------------------------------
__global__ void transpose_to_bf16(const float* __restrict__ in, __bf16* __restrict__ outT,
                                  int K, int N)
{
    __shared__ float tile[32][33];
    int k0 = blockIdx.x * 32, n0 = blockIdx.y * 32;
    int tr = threadIdx.x >> 5, tc = threadIdx.x & 31;
#pragma unroll
    for (int s = 0; s < 4; ++s)
        tile[tr + 8 * s][tc] = in[(size_t)(k0 + tr + 8 * s) * N + n0 + tc];
    __syncthreads();
#pragma unroll
    for (int s = 0; s < 4; ++s)
        outT[(size_t)(n0 + tr + 8 * s) * K + k0 + tc] = (__bf16)tile[tc][tr + 8 * s];
}

// ---------------------------------------------------------------------------
// bf16 MFMA GEMM: C = act(A@B + bias). B pre-transposed bf16 [N][K].
// BM=BN=128, BK=32; 4 waves (2x2), each 64x64 via 4x4 mfma_f32_16x16x32_bf16.
// A_F32: A fp32 (cvt during staging) else A bf16. ACT 1: relu->bf16 out;
// ACT 2: sigmoid->fp32 out.
// ---------------------------------------------------------------------------
template <bool A_F32, int ACT>
__launch_bounds__(256)
__global__ void gemm_mfma(const void* __restrict__ Ap, const __bf16* __restrict__ BT,
                          const float* __restrict__ bias, void* __restrict__ Cp,
                          int M, int N, int K)
{
    __shared__ __bf16 Asm[128 * 32];   // [m][k], row stride 32
    __shared__ __bf16 Bsm[128 * 32];   // [n][k]

    const int t    = threadIdx.x;
    const int m0   = blockIdx.y * 128, n0 = blockIdx.x * 128;
    const int wave = t >> 6, lane = t & 63;
    const int wr   = (wave >> 1) * 64, wc = (wave & 1) * 64;
    const int quad = lane >> 4, l16 = lane & 15;
    const int sr   = t >> 1, sh = t & 1;   // staging: row, 16-elem half

    floatx4 acc[4][4];
#pragma unroll
    for (int i = 0; i < 4; ++i)
#pragma unroll
        for (int j = 0; j < 4; ++j) acc[i][j] = (floatx4){0.f, 0.f, 0.f, 0.f};

    for (int k0 = 0; k0 < K; k0 += 32) {
        // A tile: row sr, k cols k0+sh*16..+15 -> Asm[sr][sh*16..]
        if (A_F32) {
            const float* src = (const float*)Ap + (size_t)(m0 + sr) * K + k0 + sh * 16;
            __bf16 tmp[16];
#pragma unroll
            for (int q = 0; q < 4; ++q) {
                float4 v = *(const float4*)(src + q * 4);
                tmp[q * 4 + 0] = (__bf16)v.x; tmp[q * 4 + 1] = (__bf16)v.y;
                tmp[q * 4 + 2] = (__bf16)v.z; tmp[q * 4 + 3] = (__bf16)v.w;
            }
            *(bf16x8*)&Asm[sr * 32 + sh * 16 + 0] = *(bf16x8*)&tmp[0];
            *(bf16x8*)&Asm[sr * 32 + sh * 16 + 8] = *(bf16x8*)&tmp[8];
        } else {
            const __bf16* src = (const __bf16*)Ap + (size_t)(m0 + sr) * K + k0 + sh * 16;
            *(uint4*)&Asm[sr * 32 + sh * 16] = *(const uint4*)src;   // 8 bf16
            *(uint4*)&Asm[sr * 32 + sh * 16 + 8] = *(const uint4*)(src + 8);
        }
        // B tile: n row sr from BT
        {
            const __bf16* src = BT + (size_t)(n0 + sr) * K + k0 + sh * 16;
            *(uint4*)&Bsm[sr * 32 + sh * 16] = *(const uint4*)src;
            *(uint4*)&Bsm[sr * 32 + sh * 16 + 8] = *(const uint4*)(src + 8);
        }
        __syncthreads();
        bf16x8 af[4], bfr[4];
#pragma unroll
        for (int i = 0; i < 4; ++i)
            af[i] = *(const bf16x8*)&Asm[(wr + i * 16 + l16) * 32 + quad * 8];
#pragma unroll
        for (int j = 0; j < 4; ++j)
            bfr[j] = *(const bf16x8*)&Bsm[(wc + j * 16 + l16) * 32 + quad * 8];
#pragma unroll
        for (int i = 0; i < 4; ++i)
#pragma unroll
            for (int j = 0; j < 4; ++j)
                acc[i][j] = __builtin_amdgcn_mfma_f32_16x16x32_bf16(af[i], bfr[j], acc[i][j], 0, 0, 0);
        __syncthreads();
    }

    // Epilogue. C/D map (m89-verified): col = lane&15, row = quad*4 + reg.
#pragma unroll
    for (int i = 0; i < 4; ++i)
#pragma unroll
        for (int j = 0; j < 4; ++j) {
            int col = n0 + wc + j * 16 + l16;
            float b = bias[col];
#pragma unroll
            for (int r = 0; r < 4; ++r) {
                int row = m0 + wr + i * 16 + quad * 4 + r;
                float v = acc[i][j][r] + b;
                if (ACT == 1) {
                    v = fmaxf(v, 0.f);
                    ((__bf16*)Cp)[(size_t)row * N + col] = (__bf16)v;
                } else {
                    v = 1.f / (1.f + __expf(-v));
                    ((float*)Cp)[(size_t)row * N + col] = v;
                }
            }
        }
}

// ---------------------------------------------------------------------------
extern "C" void kernel_launch(void* const* d_in, const int* in_sizes, int n_in,
                              void* d_out, int out_size, void* d_ws, size_t ws_size,
                              hipStream_t stream)
{
    const float* x  = (const float*)d_in[0];
    const float* W1 = (const float*)d_in[1];
    const float* b1 = (const float*)d_in[2];
    const float* W2 = (const float*)d_in[3];
    const float* b2 = (const float*)d_in[4];
    const float* cb = (const float*)d_in[5];
    const float* W3 = (const float*)d_in[6];
    const float* b3 = (const float*)d_in[7];
    const float* W4 = (const float*)d_in[8];
    const float* b4 = (const float*)d_in[9];
    float* out = (float*)d_out;

    char* ws = (char*)d_ws;
    // h fp32 (128MB) live G1->G2 only. Aliases in that region:
    //   pv/pi (score->reduce), h2b bf16 (G3->G4, at +16MB to dodge pv/pi).
    float*  h    = (float*)(ws);
    float*  pv   = (float*)(ws);                      //  8 MB
    int*    pi   = (int*  )(ws + 8388608ull);         //  8 MB
    __bf16* h2b  = (__bf16*)(ws + 16777216ull);       // 64 MB
    float*  z32  = (float*)(ws + 134217728ull);       //  8 MB
    float*  zq   = (float*)(ws + 142606336ull);       //  8 MB
    float*  nz32 = (float*)(ws + 150994944ull);       // 64 KB
    float*  cn32 = (float*)(ws + 151060480ull);       // 32 KB
    int*    idx  = (int*  )(ws + 151093248ull);       // 64 KB
    double* acc  = (double*)(ws + 151158784ull);      //  4 KB pad
    __bf16* W3t  = (__bf16*)(ws + 151162880ull);      // 512 KB  [2048][128]
    __bf16* W4t  = (__bf16*)(ws + 151687168ull);      //   4 MB  [1024][2048]

    zero_acc_kernel<<<1, 64, 0, stream>>>(acc);
    rownorm_kernel<<<KCB / 4, 256, 0, stream>>>(cb, cn32);
    transpose_to_bf16<<<dim3(DDIM / 32, HID / 32), 256, 0, stream>>>(W3, W3t, DDIM, HID);
    transpose_to_bf16<<<dim3(HID / 32, INDIM / 32), 256, 0, stream>>>(W4, W4t, HID, INDIM);

    // h = relu(fl32(x@W1 + b1)), fp64-acc      [16384,1024]x[1024,2048]
    gemm_f64acc<1><<<dim3(HID / 64, B_ / 128), 256, 0, stream>>>(
        x, W1, b1, h, B_, HID, INDIM);
    // z32 = fl32(h@W2 + b2), fp64-acc          [16384,2048]x[2048,128]
    gemm_f64acc<0><<<dim3(DDIM / 64, B_ / 128), 256, 0, stream>>>(
        h, W2, b2, z32, B_, DDIM, HID);
    // nz32 = fl32(sum fl32(z^2))
    rownorm_kernel<<<B_ / 4, 256, 0, stream>>>(z32, nz32);
    // fp32-dist score + argmin (two-phase)
    score_argmin<<<dim3(KCB / 64, B_ / 64), 256, 0, stream>>>(z32, cb, nz32, cn32, pv, pi);
    argmin_reduce<<<B_ / 4, 256, 0, stream>>>(pv, pi, idx);
    // z_q gather + commitment loss
    gather_zq_loss<<<B_ / 4, 256, 0, stream>>>(z32, cb, idx, zq, acc);
    // h2 = relu(zq@W3 + b3) -> bf16            [16384,128]x[128,2048]
    gemm_mfma<true, 1><<<dim3(HID / 128, B_ / 128), 256, 0, stream>>>(
        (const void*)zq, W3t, b3, (void*)h2b, B_, HID, DDIM);
    // recon = sigmoid(h2@W4 + b4) -> fp32 out  [16384,2048]x[2048,1024]
    gemm_mfma<false, 2><<<dim3(INDIM / 128, B_ / 128), 256, 0, stream>>>(
        (const void*)h2b, W4t, b4, (void*)out, B_, INDIM, HID);

    finalize_kernel<<<B_ / 256, 256, 0, stream>>>(idx, acc, out);
}

// Round 6
// 2688.823 us; speedup vs baseline: 1.9010x; 1.2572x over previous
//
#include <hip/hip_runtime.h>
#include <hip/hip_bf16.h>

// VQ-VAE forward. Index path: fp32-per-op semantics w/ fp64 internal accumulation
// via f64 MFMA with runtime layout probes (self-correcting for any lane mapping).
// Argmin via packed-key atomicMin (race-free by construction). Decoder: bf16 MFMA.
// Outputs (flat fp32): recon[16384*1024], loss[1], indices-as-float[16384].

#define B_    16384
#define INDIM 1024
#define HID   2048
#define KCB   8192
#define DDIM  128

typedef __bf16  bf16x8   __attribute__((ext_vector_type(8)));
typedef float   floatx4  __attribute__((ext_vector_type(4)));
typedef double  doublex4 __attribute__((ext_vector_type(4)));

__device__ __forceinline__ unsigned long long pack_key(float d, int code)
{
    unsigned int u = __float_as_uint(d);
    u = (u & 0x80000000u) ? ~u : (u | 0x80000000u);   // total order matching float <
    return ((unsigned long long)u << 32) | (unsigned int)code;
}

// ---------------------------------------------------------------------------
// fp32-in GEMM, fp64 MFMA accumulate, single fp32 rounding (+opt relu).
// BM=128 BN=64 BK=16; 4 waves 2x2, wave tile 64x32 via 4x2 mfma_f64_16x16x4.
// Epilogue positions come from runtime layout probes (rowmap/colmap).
// ---------------------------------------------------------------------------
template <int ACT>
__launch_bounds__(256)
__global__ void gemm_f64_mfma(const float* __restrict__ A, const float* __restrict__ Bm,
                              const float* __restrict__ bias, float* __restrict__ Cout,
                              int M, int N, int K)
{
    __shared__ double As[16][130];   // [k][m]
    __shared__ double Bs[16][66];    // [k][n]

    const int t    = threadIdx.x;
    const int m0   = blockIdx.y * 128, n0 = blockIdx.x * 64;
    const int wave = t >> 6, lane = t & 63;
    const int wr   = (wave >> 1) * 64, wc = (wave & 1) * 32;
    const int quad = lane >> 4, l16 = lane & 15;

    // Layout probe: D[m][n] = 4m (prow) / 4n (pcol) for ANY bijective lane maps.
    doublex4 p0 = {0.0, 0.0, 0.0, 0.0};
    doublex4 prow = __builtin_amdgcn_mfma_f64_16x16x4f64((double)l16, 1.0, p0, 0, 0, 0);
    doublex4 pcol = __builtin_amdgcn_mfma_f64_16x16x4f64(1.0, (double)l16, p0, 0, 0, 0);
    int rowmap[4], colmap[4];
#pragma unroll
    for (int r = 0; r < 4; ++r) {
        rowmap[r] = (int)(prow[r] * 0.25);
        colmap[r] = (int)(pcol[r] * 0.25);
    }

    doublex4 acc[4][2];
#pragma unroll
    for (int i = 0; i < 4; ++i)
#pragma unroll
        for (int j = 0; j < 2; ++j) acc[i][j] = (doublex4){0.0, 0.0, 0.0, 0.0};

    for (int k0 = 0; k0 < K; k0 += 16) {
#pragma unroll
        for (int s = 0; s < 2; ++s) {            // A tile 128x16
            int chunk = t + s * 256;
            int r = chunk >> 2, c4 = (chunk & 3) * 4;
            float4 v = *(const float4*)(A + (size_t)(m0 + r) * K + k0 + c4);
            As[c4 + 0][r] = (double)v.x; As[c4 + 1][r] = (double)v.y;
            As[c4 + 2][r] = (double)v.z; As[c4 + 3][r] = (double)v.w;
        }
        {                                         // B tile 16x64
            int r = t >> 4, c4 = (t & 15) * 4;
            float4 v = *(const float4*)(Bm + (size_t)(k0 + r) * N + n0 + c4);
            Bs[r][c4 + 0] = (double)v.x; Bs[r][c4 + 1] = (double)v.y;
            Bs[r][c4 + 2] = (double)v.z; Bs[r][c4 + 3] = (double)v.w;
        }
        __syncthreads();
#pragma unroll
        for (int ks = 0; ks < 16; ks += 4) {
            int ka = ks + quad;
            double a[4], b[2];
#pragma unroll
            for (int i = 0; i < 4; ++i) a[i] = As[ka][wr + i * 16 + l16];
#pragma unroll
            for (int j = 0; j < 2; ++j) b[j] = Bs[ka][wc + j * 16 + l16];
#pragma unroll
            for (int i = 0; i < 4; ++i)
#pragma unroll
                for (int j = 0; j < 2; ++j)
                    acc[i][j] = __builtin_amdgcn_mfma_f64_16x16x4f64(a[i], b[j], acc[i][j], 0, 0, 0);
        }
        __syncthreads();
    }

#pragma unroll
    for (int i = 0; i < 4; ++i)
#pragma unroll
        for (int j = 0; j < 2; ++j)
#pragma unroll
            for (int r = 0; r < 4; ++r) {
                int row = m0 + wr + i * 16 + rowmap[r];
                int col = n0 + wc + j * 16 + colmap[r];
                float f = (float)(acc[i][j][r] + (double)bias[col]);  // single fp32 round
                if (ACT == 1) f = fmaxf(f, 0.f);
                Cout[(size_t)row * N + col] = f;
            }
}

// ---------------------------------------------------------------------------
// rownorm32[k] = fl32( sum_fp64( fl32(row[k][d]^2) ) ). One wave per row.
// ---------------------------------------------------------------------------
__global__ void rownorm_kernel(const float* __restrict__ M, float* __restrict__ nrm)
{
    int k = blockIdx.x * 4 + (threadIdx.x >> 6);
    int lane = threadIdx.x & 63;
    float2 c = *(const float2*)(M + (size_t)k * DDIM + lane * 2);
    float q0 = c.x * c.x;
    float q1 = c.y * c.y;
    double s = (double)q0 + (double)q1;
#pragma unroll
    for (int off = 32; off > 0; off >>= 1) s += __shfl_down(s, off);
    if (lane == 0) nrm[k] = (float)s;
}

// ---------------------------------------------------------------------------
// Score: f64 MFMA z.c per (64-row,128-code) tile; fp32 dist chain
// d = fl32(fl32(nz - 2*s32) + cn); per-row argmin via packed-key LDS atomicMin
// (merges all waves/quads/halves race-free), then global atomicMin into gbest.
// ---------------------------------------------------------------------------
__launch_bounds__(256)
__global__ void score_argmin_mfma(const float* __restrict__ z, const float* __restrict__ cb,
                                  const float* __restrict__ nz32, const float* __restrict__ cn32,
                                  unsigned long long* __restrict__ gbest)
{
    __shared__ double zs[16][66];    // [k][m]
    __shared__ double cs[16][130];   // [k][n]
    __shared__ unsigned long long best[64];

    const int t    = threadIdx.x;
    const int m0   = blockIdx.y * 64;    // rows
    const int n0   = blockIdx.x * 128;   // codes
    const int wave = t >> 6, lane = t & 63;
    const int wr   = (wave >> 1) * 32, wc = (wave & 1) * 64;
    const int quad = lane >> 4, l16 = lane & 15;

    if (t < 64) best[t] = ~0ull;

    doublex4 p0 = {0.0, 0.0, 0.0, 0.0};
    doublex4 prow = __builtin_amdgcn_mfma_f64_16x16x4f64((double)l16, 1.0, p0, 0, 0, 0);
    doublex4 pcol = __builtin_amdgcn_mfma_f64_16x16x4f64(1.0, (double)l16, p0, 0, 0, 0);
    int rowmap[4], colmap[4];
#pragma unroll
    for (int r = 0; r < 4; ++r) {
        rowmap[r] = (int)(prow[r] * 0.25);
        colmap[r] = (int)(pcol[r] * 0.25);
    }

    doublex4 acc[2][4];
#pragma unroll
    for (int i = 0; i < 2; ++i)
#pragma unroll
        for (int j = 0; j < 4; ++j) acc[i][j] = (doublex4){0.0, 0.0, 0.0, 0.0};

    for (int k0 = 0; k0 < DDIM; k0 += 16) {
        {                                         // z tile 64x16
            int r = t >> 2, c4 = (t & 3) * 4;
            float4 v = *(const float4*)(z + (size_t)(m0 + r) * DDIM + k0 + c4);
            zs[c4 + 0][r] = (double)v.x; zs[c4 + 1][r] = (double)v.y;
            zs[c4 + 2][r] = (double)v.z; zs[c4 + 3][r] = (double)v.w;
        }
#pragma unroll
        for (int s = 0; s < 2; ++s) {             // cb tile 128x16
            int chunk = t + s * 256;
            int rr = chunk >> 2, c4 = (chunk & 3) * 4;
            float4 v = *(const float4*)(cb + (size_t)(n0 + rr) * DDIM + k0 + c4);
            cs[c4 + 0][rr] = (double)v.x; cs[c4 + 1][rr] = (double)v.y;
            cs[c4 + 2][rr] = (double)v.z; cs[c4 + 3][rr] = (double)v.w;
        }
        __syncthreads();
#pragma unroll
        for (int ks = 0; ks < 16; ks += 4) {
            int ka = ks + quad;
            double a[2], b[4];
#pragma unroll
            for (int i = 0; i < 2; ++i) a[i] = zs[ka][wr + i * 16 + l16];
#pragma unroll
            for (int j = 0; j < 4; ++j) b[j] = cs[ka][wc + j * 16 + l16];
#pragma unroll
            for (int i = 0; i < 2; ++i)
#pragma unroll
                for (int j = 0; j < 4; ++j)
                    acc[i][j] = __builtin_amdgcn_mfma_f64_16x16x4f64(a[i], b[j], acc[i][j], 0, 0, 0);
        }
        __syncthreads();
    }

    // Per (i,r): one local row; merge the 4 j-codes, then LDS atomicMin.
#pragma unroll
    for (int i = 0; i < 2; ++i)
#pragma unroll
        for (int r = 0; r < 4; ++r) {
            int   lrow = wr + i * 16 + rowmap[r];
            float nz   = nz32[m0 + lrow];
            float bd   = 3.4e38f; int bc = 0x7fffffff;
#pragma unroll
            for (int j = 0; j < 4; ++j) {
                int   code = n0 + wc + j * 16 + colmap[r];
                float s32  = (float)acc[i][j][r];
                float d    = (nz - 2.0f * s32) + cn32[code];
                if (d < bd || (d == bd && code < bc)) { bd = d; bc = code; }
            }
            atomicMin(&best[lrow], pack_key(bd, bc));
        }
    __syncthreads();
    if (t < 64) atomicMin(&gbest[m0 + t], best[t]);
}

__global__ void init_gbest(unsigned long long* __restrict__ g)
{
    g[blockIdx.x * 256 + threadIdx.x] = ~0ull;
}

// Gather z_q = codebook[idx] (fp32) and accumulate sum((z_q - z32)^2) in fp64.
__global__ void gather_zq_loss(const float* __restrict__ z, const float* __restrict__ cb,
                               const unsigned long long* __restrict__ gbest,
                               float* __restrict__ zq, double* __restrict__ acc)
{
    int r = blockIdx.x * 4 + (threadIdx.x >> 6);
    int lane = threadIdx.x & 63;
    int k = (int)(gbest[r] & 0xffffffffull);
    float2 zv = *(const float2*)(z  + (size_t)r * DDIM + lane * 2);
    float2 cv = *(const float2*)(cb + (size_t)k * DDIM + lane * 2);
    *(float2*)(zq + (size_t)r * DDIM + lane * 2) = cv;
    double dx = (double)cv.x - (double)zv.x, dy = (double)cv.y - (double)zv.y;
    double s = dx * dx + dy * dy;
#pragma unroll
    for (int off = 32; off > 0; off >>= 1) s += __shfl_down(s, off);
    if (lane == 0) atomicAdd(acc, s);
}

__global__ void zero_acc_kernel(double* acc)
{
    if (threadIdx.x == 0 && blockIdx.x == 0) *acc = 0.0;
}

__global__ void finalize_kernel(const unsigned long long* __restrict__ gbest,
                                const double* __restrict__ acc, float* __restrict__ out)
{
    int tid = blockIdx.x * 256 + threadIdx.x;
    if (tid < B_) out[16777217 + tid] = (float)(int)(gbest[tid] & 0xffffffffull);
    if (tid == 0) out[16777216] = (float)((*acc) * 1.25 / (double)(B_ * DDIM));
}

// ---------------------------------------------------------------------------
// One-time weight transpose+cvt: in fp32 [K][N] -> out bf16 [N][K].
// ---------------------------------------------------------------------------
__global__ void transpose_to_bf16(const float* __restrict__ in, __bf16* __restrict__ outT,
                                  int K, int N)
{
    __shared__ float tile[32][33];
    int k0 = blockIdx.x * 32, n0 = blockIdx.y * 32;
    int tr = threadIdx.x >> 5, tc = threadIdx.x & 31;
#pragma unroll
    for (int s = 0; s < 4; ++s)
        tile[tr + 8 * s][tc] = in[(size_t)(k0 + tr + 8 * s) * N + n0 + tc];
    __syncthreads();
#pragma unroll
    for (int s = 0; s < 4; ++s)
        outT[(size_t)(n0 + tr + 8 * s) * K + k0 + tc] = (__bf16)tile[tc][tr + 8 * s];
}

// ---------------------------------------------------------------------------
// bf16 MFMA GEMM (decoder, layout HW-validated R4): C = act(A@B + bias).
// ---------------------------------------------------------------------------
template <bool A_F32, int ACT>
__launch_bounds__(256)
__global__ void gemm_mfma(const void* __restrict__ Ap, const __bf16* __restrict__ BT,
                          const float* __restrict__ bias, void* __restrict__ Cp,
                          int M, int N, int K)
{
    __shared__ __bf16 Asm[128 * 32];
    __shared__ __bf16 Bsm[128 * 32];

    const int t    = threadIdx.x;
    const int m0   = blockIdx.y * 128, n0 = blockIdx.x * 128;
    const int wave = t >> 6, lane = t & 63;
    const int wr   = (wave >> 1) * 64, wc = (wave & 1) * 64;
    const int quad = lane >> 4, l16 = lane & 15;
    const int sr   = t >> 1, sh = t & 1;

    floatx4 acc[4][4];
#pragma unroll
    for (int i = 0; i < 4; ++i)
#pragma unroll
        for (int j = 0; j < 4; ++j) acc[i][j] = (floatx4){0.f, 0.f, 0.f, 0.f};

    for (int k0 = 0; k0 < K; k0 += 32) {
        if (A_F32) {
            const float* src = (const float*)Ap + (size_t)(m0 + sr) * K + k0 + sh * 16;
            __bf16 tmp[16];
#pragma unroll
            for (int q = 0; q < 4; ++q) {
                float4 v = *(const float4*)(src + q * 4);
                tmp[q * 4 + 0] = (__bf16)v.x; tmp[q * 4 + 1] = (__bf16)v.y;
                tmp[q * 4 + 2] = (__bf16)v.z; tmp[q * 4 + 3] = (__bf16)v.w;
            }
            *(bf16x8*)&Asm[sr * 32 + sh * 16 + 0] = *(bf16x8*)&tmp[0];
            *(bf16x8*)&Asm[sr * 32 + sh * 16 + 8] = *(bf16x8*)&tmp[8];
        } else {
            const __bf16* src = (const __bf16*)Ap + (size_t)(m0 + sr) * K + k0 + sh * 16;
            *(uint4*)&Asm[sr * 32 + sh * 16] = *(const uint4*)src;
            *(uint4*)&Asm[sr * 32 + sh * 16 + 8] = *(const uint4*)(src + 8);
        }
        {
            const __bf16* src = BT + (size_t)(n0 + sr) * K + k0 + sh * 16;
            *(uint4*)&Bsm[sr * 32 + sh * 16] = *(const uint4*)src;
            *(uint4*)&Bsm[sr * 32 + sh * 16 + 8] = *(const uint4*)(src + 8);
        }
        __syncthreads();
        bf16x8 af[4], bfr[4];
#pragma unroll
        for (int i = 0; i < 4; ++i)
            af[i] = *(const bf16x8*)&Asm[(wr + i * 16 + l16) * 32 + quad * 8];
#pragma unroll
        for (int j = 0; j < 4; ++j)
            bfr[j] = *(const bf16x8*)&Bsm[(wc + j * 16 + l16) * 32 + quad * 8];
#pragma unroll
        for (int i = 0; i < 4; ++i)
#pragma unroll
            for (int j = 0; j < 4; ++j)
                acc[i][j] = __builtin_amdgcn_mfma_f32_16x16x32_bf16(af[i], bfr[j], acc[i][j], 0, 0, 0);
        __syncthreads();
    }

#pragma unroll
    for (int i = 0; i < 4; ++i)
#pragma unroll
        for (int j = 0; j < 4; ++j) {
            int col = n0 + wc + j * 16 + l16;
            float b = bias[col];
#pragma unroll
            for (int r = 0; r < 4; ++r) {
                int row = m0 + wr + i * 16 + quad * 4 + r;
                float v = acc[i][j][r] + b;
                if (ACT == 1) {
                    v = fmaxf(v, 0.f);
                    ((__bf16*)Cp)[(size_t)row * N + col] = (__bf16)v;
                } else {
                    v = 1.f / (1.f + __expf(-v));
                    ((float*)Cp)[(size_t)row * N + col] = v;
                }
            }
        }
}

// ---------------------------------------------------------------------------
extern "C" void kernel_launch(void* const* d_in, const int* in_sizes, int n_in,
                              void* d_out, int out_size, void* d_ws, size_t ws_size,
                              hipStream_t stream)
{
    const float* x  = (const float*)d_in[0];
    const float* W1 = (const float*)d_in[1];
    const float* b1 = (const float*)d_in[2];
    const float* W2 = (const float*)d_in[3];
    const float* b2 = (const float*)d_in[4];
    const float* cb = (const float*)d_in[5];
    const float* W3 = (const float*)d_in[6];
    const float* b3 = (const float*)d_in[7];
    const float* W4 = (const float*)d_in[8];
    const float* b4 = (const float*)d_in[9];
    float* out = (float*)d_out;

    char* ws = (char*)d_ws;
    // h fp32 (128MB) live G1->G2 only; h2b bf16 (G3->G4) aliases at +16MB.
    float*  h    = (float*)(ws);
    __bf16* h2b  = (__bf16*)(ws + 16777216ull);       // 64 MB
    float*  z32  = (float*)(ws + 134217728ull);       //  8 MB
    float*  zq   = (float*)(ws + 142606336ull);       //  8 MB
    float*  nz32 = (float*)(ws + 150994944ull);       // 64 KB
    float*  cn32 = (float*)(ws + 151060480ull);       // 32 KB
    unsigned long long* gbest = (unsigned long long*)(ws + 151093248ull); // 128 KB
    double* acc  = (double*)(ws + 151224320ull);      // 8 B (4KB pad)
    __bf16* W3t  = (__bf16*)(ws + 151228416ull);      // 512 KB [2048][128]
    __bf16* W4t  = (__bf16*)(ws + 151752704ull);      //   4 MB [1024][2048]

    zero_acc_kernel<<<1, 64, 0, stream>>>(acc);
    init_gbest<<<B_ / 256, 256, 0, stream>>>(gbest);
    rownorm_kernel<<<KCB / 4, 256, 0, stream>>>(cb, cn32);
    transpose_to_bf16<<<dim3(DDIM / 32, HID / 32), 256, 0, stream>>>(W3, W3t, DDIM, HID);
    transpose_to_bf16<<<dim3(HID / 32, INDIM / 32), 256, 0, stream>>>(W4, W4t, HID, INDIM);

    // h = relu(fl32(x@W1 + b1)), f64 MFMA      [16384,1024]x[1024,2048]
    gemm_f64_mfma<1><<<dim3(HID / 64, B_ / 128), 256, 0, stream>>>(
        x, W1, b1, h, B_, HID, INDIM);
    // z32 = fl32(h@W2 + b2), f64 MFMA          [16384,2048]x[2048,128]
    gemm_f64_mfma<0><<<dim3(DDIM / 64, B_ / 128), 256, 0, stream>>>(
        h, W2, b2, z32, B_, DDIM, HID);
    // nz32 = fl32(sum fl32(z^2))
    rownorm_kernel<<<B_ / 4, 256, 0, stream>>>(z32, nz32);
    // f64-MFMA score + race-free fused argmin
    score_argmin_mfma<<<dim3(KCB / 128, B_ / 64), 256, 0, stream>>>(
        z32, cb, nz32, cn32, gbest);
    // z_q gather + commitment loss
    gather_zq_loss<<<B_ / 4, 256, 0, stream>>>(z32, cb, gbest, zq, acc);
    // h2 = relu(zq@W3 + b3) -> bf16            [16384,128]x[128,2048]
    gemm_mfma<true, 1><<<dim3(HID / 128, B_ / 128), 256, 0, stream>>>(
        (const void*)zq, W3t, b3, (void*)h2b, B_, HID, DDIM);
    // recon = sigmoid(h2@W4 + b4) -> fp32 out  [16384,2048]x[2048,1024]
    gemm_mfma<false, 2><<<dim3(INDIM / 128, B_ / 128), 256, 0, stream>>>(
        (const void*)h2b, W4t, b4, (void*)out, B_, INDIM, HID);

    finalize_kernel<<<B_ / 256, 256, 0, stream>>>(gbest, acc, out);
}